// Round 9
// baseline (472.534 us; speedup 1.0000x reference)
//
#include <hip/hip_runtime.h>
#include <hip/hip_bf16.h>

#define N      4096
#define NFEAT  512
#define NHID   64
#define NHEADS 8
#define NCLASS 40
#define ALPHA  0.2f
#define LOG2E  1.44269504f

typedef unsigned short u16;
typedef unsigned int   u32;
typedef __attribute__((ext_vector_type(8))) short bf16x8;
typedef __attribute__((ext_vector_type(4))) float f32x4;

// bf16 bits -> f32
__device__ __forceinline__ float b2f(u16 u) {
    return __uint_as_float(((u32)u) << 16);
}
// RNE-rounded value kept in HIGH 16 bits
__device__ __forceinline__ u32 rnd_hi(float f) {
    u32 u = __float_as_uint(f);
    return u + 0x7FFFu + ((u >> 16) & 1u);
}
// pack two f32 -> two bf16 (lo in low 16) via HW v_cvt_pk_bf16_f32 (gfx950)
__device__ __forceinline__ u32 pk2(float lo, float hi) {
    __hip_bfloat162 h = __float22bfloat162_rn(make_float2(lo, hi));
    return *(u32*)&h;
}
// single f32 -> bf16 bits (RNE)
__device__ __forceinline__ u16 f2b(float f) {
    return (u16)(rnd_hi(f) >> 16);
}
// masked exp2 of leaky-relu in log2 domain: raw v_exp_f32, no OCML guards
__device__ __forceinline__ float mexp(int m, float t) {
    return m ? __builtin_amdgcn_exp2f(fmaxf(t, ALPHA * t)) : 0.f;
}
// constant all-ones bf16 B-fragment (every output column = row sum)
__device__ __forceinline__ bf16x8 ones_frag() {
    union { u16 u[8]; bf16x8 v; } o;
    #pragma unroll
    for (int j = 0; j < 8; ++j) o.u[j] = 0x3F80;
    return o.v;
}

// ---------------- KCX: x f32 -> xb bf16 (same layout) ---------------------------
__global__ __launch_bounds__(256) void kcx(const float* __restrict__ x,
                                           u16* __restrict__ xb) {
    const int g = blockIdx.x * 256 + threadIdx.x;       // 262144 threads x 8 elems
    const size_t base = (size_t)g * 8;
    float4 v0 = *(const float4*)&x[base];
    float4 v1 = *(const float4*)&x[base + 4];
    uint4 o;
    o.x = pk2(v0.x, v0.y); o.y = pk2(v0.z, v0.w);
    o.z = pk2(v1.x, v1.y); o.w = pk2(v1.z, v1.w);
    *(uint4*)&xb[base] = o;
}

// ---------------- KCW: W1 [h][f][d] f32 -> W1b bf16 [h][d][f] -------------------
__global__ __launch_bounds__(256) void kcw(const float* __restrict__ W1,
                                           u16* __restrict__ W1b) {
    __shared__ float ts[64 * 68];   // [f-local][d], pitch 68
    const int t  = threadIdx.x;
    const int f0 = blockIdx.x * 64;
    const int h  = blockIdx.y;
    #pragma unroll
    for (int i = 0; i < 4; ++i) {
        int flat = t + 256 * i;
        int row = flat >> 4;                    // f-local
        int c4  = (flat & 15) * 4;              // d
        *(float4*)&ts[row * 68 + c4] =
            *(const float4*)&W1[((size_t)h * 512 + f0 + row) * 64 + c4];
    }
    __syncthreads();
    const int d  = t >> 2;
    const int fs = (t & 3) * 16;
    u32 p[8];
    #pragma unroll
    for (int j = 0; j < 8; ++j)
        p[j] = pk2(ts[(fs + 2 * j) * 68 + d], ts[(fs + 2 * j + 1) * 68 + d]);
    u32* dst = (u32*)&W1b[((size_t)(h * 64 + d)) * 512 + f0 + fs];
    *(uint4*)dst       = make_uint4(p[0], p[1], p[2], p[3]);
    *(uint4*)(dst + 4) = make_uint4(p[4], p[5], p[6], p[7]);
}

// ---------------- K1M: Wh1T[h][d][n] = bf16( sum_f xb[n,f] * W1b[h,d,f] ) -------
__global__ __launch_bounds__(256, 4) void k1m_gemm1(const u16* __restrict__ xb,
                                                    const u16* __restrict__ W1b,
                                                    u16* __restrict__ Wh1T) {
    __shared__ u16 xs[64 * 72];    // [n-local][f-chunk], pitch 72
    __shared__ u16 wvs[64 * 72];   // [d][f-chunk]
    const int t    = threadIdx.x;
    const int n0   = blockIdx.x * 64;
    const int h    = blockIdx.y;
    const int lane = t & 63;
    const int l15  = lane & 15;
    const int q    = lane >> 4;
    const int wrow = (t >> 6) * 16;
    f32x4 acc[4];
    #pragma unroll
    for (int df = 0; df < 4; ++df)
        #pragma unroll
        for (int r = 0; r < 4; ++r) acc[df][r] = 0.f;
    for (int f0 = 0; f0 < 512; f0 += 64) {
        uint4 sx[2], sw[2];
        #pragma unroll
        for (int i = 0; i < 2; ++i) {
            int flat = t + 256 * i;
            int row = flat >> 3;
            int c8  = (flat & 7) * 8;
            sx[i] = *(const uint4*)&xb[(size_t)(n0 + row) * 512 + f0 + c8];
            sw[i] = *(const uint4*)&W1b[((size_t)(h * 64 + row)) * 512 + f0 + c8];
        }
        __syncthreads();
        #pragma unroll
        for (int i = 0; i < 2; ++i) {
            int flat = t + 256 * i;
            int row = flat >> 3;
            int c8  = (flat & 7) * 8;
            *(uint4*)&xs[row * 72 + c8]  = sx[i];
            *(uint4*)&wvs[row * 72 + c8] = sw[i];
        }
        __syncthreads();
        #pragma unroll
        for (int ks = 0; ks < 2; ++ks) {
            int k0 = ks * 32 + q * 8;
            bf16x8 a = *(const bf16x8*)&xs[(wrow + l15) * 72 + k0];
            #pragma unroll
            for (int df = 0; df < 4; ++df) {
                bf16x8 b = *(const bf16x8*)&wvs[(df * 16 + l15) * 72 + k0];
                acc[df] = __builtin_amdgcn_mfma_f32_16x16x32_bf16(a, b, acc[df], 0, 0, 0);
            }
        }
    }
    #pragma unroll
    for (int df = 0; df < 4; ++df) {
        uint2 o;
        o.x = pk2(acc[df][0], acc[df][1]);
        o.y = pk2(acc[df][2], acc[df][3]);
        *(uint2*)&Wh1T[((size_t)(h * 64 + df * 16 + l15)) * 4096 + n0 + wrow + q * 4] = o;
    }
}

// ---------------- K2: F1/F2 (pre-scaled by log2e) from Wh1T bf16 ----------------
__global__ __launch_bounds__(256) void k2_f12(const u16* __restrict__ Wh1T,
                                              const float* __restrict__ a1,
                                              float* __restrict__ F1,
                                              float* __restrict__ F2) {
    const int g = blockIdx.x * 256 + threadIdx.x;   // 32768 threads
    const int h = g >> 12;
    const int n = g & 4095;
    float s1 = 0.f, s2 = 0.f;
    #pragma unroll 8
    for (int d = 0; d < 64; ++d) {
        float v = b2f(Wh1T[((size_t)(h * 64 + d)) * 4096 + n]);
        s1 += v * a1[h * 128 + d];
        s2 += v * a1[h * 128 + 64 + d];
    }
    F1[h * 4096 + n] = s1 * LOG2E;
    F2[h * 4096 + n] = s2 * LOG2E;
}

// ---------------- K3: layer-1 attention partials via MFMA -----------------------
// A-frags built in registers (R6-verified mapping), B-tile in LDS (64 rows only),
// denominator via constant all-ones B-frag. LDS 17.4 KB -> 5 blocks/CU at (256,5).
// grid (64 n-tiles, 8 heads, 2 m-chunks) x 256.
__global__ __launch_bounds__(256, 5) void k3_attn1(const int* __restrict__ adj1,
                                                   const u16* __restrict__ Wh1T,
                                                   const float* __restrict__ F1,
                                                   const float* __restrict__ F2,
                                                   float* __restrict__ pacc1,
                                                   float* __restrict__ pz1) {
    __shared__ u16 whT[64 * 136];     // B-tile, data rows d=0..63 only
    const int t     = threadIdx.x;
    const int n0    = blockIdx.x * 64;
    const int h     = blockIdx.y;
    const int chunk = blockIdx.z;
    const int lane  = t & 63;
    const int l15   = lane & 15;
    const int q     = lane >> 4;
    const int wrow  = (t >> 6) * 16;
    const int ar    = wrow + l15;             // this lane's A row (n-local)
    const bf16x8 bones = ones_frag();

    f32x4 acc[5];
    #pragma unroll
    for (int df = 0; df < 5; ++df)
        #pragma unroll
        for (int r = 0; r < 4; ++r) acc[df][r] = 0.f;
    const float  F1v  = F1[h * N + n0 + ar];
    const int*   arow = &adj1[(size_t)(n0 + ar) * N];
    const float* frow = &F2[h * N];

    const int mbeg = chunk * 2048;
    for (int m0 = mbeg; m0 < mbeg + 2048; m0 += 128) {
        // ---- adj loads first (needed soonest) ----
        int4 a[8];
        #pragma unroll
        for (int ks = 0; ks < 4; ++ks) {
            a[2 * ks]     = *(const int4*)&arow[m0 + ks * 32 + q * 8];
            a[2 * ks + 1] = *(const int4*)&arow[m0 + ks * 32 + q * 8 + 4];
        }
        // ---- B-tile staging loads (needed after barrier) ----
        uint4 st[4];
        #pragma unroll
        for (int i = 0; i < 4; ++i) {
            int flat = t + 256 * i;           // 64 rows x 16 chunks
            int row = flat >> 4;
            int c8  = (flat & 15) * 8;
            st[i] = *(const uint4*)&Wh1T[((size_t)(h * 64 + row)) * 4096 + m0 + c8];
        }
        // ---- mask-gen into register A-frags (HW exp2 + HW bf16 pack) ----
        bf16x8 aw[4];
        #pragma unroll
        for (int ks = 0; ks < 4; ++ks) {
            float4 g0 = *(const float4*)&frow[m0 + ks * 32 + q * 8];
            float4 g1 = *(const float4*)&frow[m0 + ks * 32 + q * 8 + 4];
            float w0 = mexp(a[2 * ks].x,     F1v + g0.x);
            float w1 = mexp(a[2 * ks].y,     F1v + g0.y);
            float w2 = mexp(a[2 * ks].z,     F1v + g0.z);
            float w3 = mexp(a[2 * ks].w,     F1v + g0.w);
            float w4 = mexp(a[2 * ks + 1].x, F1v + g1.x);
            float w5 = mexp(a[2 * ks + 1].y, F1v + g1.y);
            float w6 = mexp(a[2 * ks + 1].z, F1v + g1.z);
            float w7 = mexp(a[2 * ks + 1].w, F1v + g1.w);
            union { u32 u[4]; bf16x8 v; } pk;
            pk.u[0] = pk2(w0, w1); pk.u[1] = pk2(w2, w3);
            pk.u[2] = pk2(w4, w5); pk.u[3] = pk2(w6, w7);
            aw[ks] = pk.v;
        }
        __syncthreads();                      // prev iter's whT reads complete
        #pragma unroll
        for (int i = 0; i < 4; ++i) {
            int flat = t + 256 * i;
            int row = flat >> 4;
            int c8  = (flat & 15) * 8;
            *(uint4*)&whT[row * 136 + c8] = st[i];
        }
        __syncthreads();
        // ---- compute: 4 K-steps x (4 data frags + ones frag) ----
        #pragma unroll
        for (int ks = 0; ks < 4; ++ks) {
            int k0 = ks * 32 + q * 8;
            #pragma unroll
            for (int df = 0; df < 4; ++df) {
                bf16x8 b = *(const bf16x8*)&whT[(df * 16 + l15) * 136 + k0];
                acc[df] = __builtin_amdgcn_mfma_f32_16x16x32_bf16(aw[ks], b, acc[df], 0, 0, 0);
            }
            acc[4] = __builtin_amdgcn_mfma_f32_16x16x32_bf16(aw[ks], bones, acc[4], 0, 0, 0);
        }
    }
    // raw partials; denominator = acc[4] (all columns equal the row sum)
    const size_t rowbase = (size_t)(chunk * 8 + h) * 4096 + n0;
    #pragma unroll
    for (int r = 0; r < 4; ++r) {
        int nl = wrow + q * 4 + r;
        if (l15 == 0) pz1[rowbase + nl] = acc[4][r];
        #pragma unroll
        for (int df = 0; df < 4; ++df)
            pacc1[(rowbase + nl) * 64 + df * 16 + l15] = acc[df][r];
    }
}

// ---------------- K3b: reduce 2 chunks, normalize, ELU -> h1 f32 ----------------
__global__ __launch_bounds__(256) void k3b_norm(const float* __restrict__ pacc1,
                                                const float* __restrict__ pz1,
                                                float* __restrict__ h1) {
    const int g = blockIdx.x * 256 + threadIdx.x;
    const int d = g & 63;
    const int h = (g >> 6) & 7;
    const int n = g >> 9;
    const size_t i0 = (size_t)h * 4096 + n;
    float s = pacc1[i0 * 64 + d] + pacc1[(i0 + 8 * 4096) * 64 + d];
    float z = pz1[i0] + pz1[i0 + 8 * 4096];
    float v = s / fmaxf(z, 1e-30f);
    h1[(size_t)n * 512 + h * 64 + d] = v > 0.f ? v : __expf(v) - 1.f;
}

// ---------------- K4: Wh2[n][c] = h1[n,:] @ Wo[:,c]  (f32) ----------------------
__global__ __launch_bounds__(256) void k4_gemm2(const float* __restrict__ h1,
                                                const float* __restrict__ Wo,
                                                float* __restrict__ Wh2) {
    const int t = threadIdx.x;
    const int c = t & 63;
    const int n = blockIdx.x * 4 + (t >> 6);
    if (c < NCLASS) {
        const float* hrow = &h1[(size_t)n * 512];
        float acc = 0.f;
        #pragma unroll 8
        for (int f = 0; f < 512; ++f)
            acc += hrow[f] * Wo[f * NCLASS + c];
        Wh2[(size_t)n * NCLASS + c] = acc;
    }
}

// ---------------- K4b: F1o/F2o (pre-scaled) + Wh2T bf16 [c][n] ------------------
__global__ __launch_bounds__(256) void k4b_fo(const float* __restrict__ Wh2,
                                              const float* __restrict__ ao,
                                              float* __restrict__ F1o,
                                              float* __restrict__ F2o,
                                              u16* __restrict__ Wh2T) {
    const int n = blockIdx.x * 256 + threadIdx.x;
    float s1 = 0.f, s2 = 0.f;
    #pragma unroll
    for (int c = 0; c < NCLASS; ++c) {
        float v = Wh2[(size_t)n * NCLASS + c];
        s1 += v * ao[c];
        s2 += v * ao[NCLASS + c];
        Wh2T[(size_t)c * 4096 + n] = f2b(v);
    }
    F1o[n] = s1 * LOG2E;
    F2o[n] = s2 * LOG2E;
}

// ---------------- K5a: layer-2 attention partials via MFMA ----------------------
// Same structure as k3: A in regs, B 48 rows LDS (13 KB), ones-frag denominator.
// grid (64 n-tiles, 16 m-chunks) x 256.
__global__ __launch_bounds__(256, 6) void k5a_attn2(const int* __restrict__ adj0,
                                                    const u16* __restrict__ Wh2T,
                                                    const float* __restrict__ F1o,
                                                    const float* __restrict__ F2o,
                                                    float* __restrict__ pacc,
                                                    float* __restrict__ pz) {
    __shared__ u16 whT[48 * 136];     // rows 0..39 data, 40..47 zero
    const int t     = threadIdx.x;
    const int n0    = blockIdx.x * 64;
    const int chunk = blockIdx.y;
    const int mbase = chunk * 256;
    const int lane  = t & 63;
    const int l15   = lane & 15;
    const int q     = lane >> 4;
    const int wrow  = (t >> 6) * 16;
    const int ar    = wrow + l15;
    const bf16x8 bones = ones_frag();
    // zero pad rows 40..47 (read by df=2 frag, lanes l15>=8)
    #pragma unroll
    for (int i = 0; i < 5; ++i) {
        int idx = t + 256 * i;                // 8*136 = 1088
        if (idx < 1088) whT[40 * 136 + idx] = 0;
    }
    f32x4 acc[4];
    #pragma unroll
    for (int df = 0; df < 4; ++df)
        #pragma unroll
        for (int r = 0; r < 4; ++r) acc[df][r] = 0.f;
    const float  F1v  = F1o[n0 + ar];
    const int*   arow = &adj0[(size_t)(n0 + ar) * N];

    for (int mt = 0; mt < 2; ++mt) {
        int m0 = mbase + mt * 128;
        int4 a[8];
        #pragma unroll
        for (int ks = 0; ks < 4; ++ks) {
            a[2 * ks]     = *(const int4*)&arow[m0 + ks * 32 + q * 8];
            a[2 * ks + 1] = *(const int4*)&arow[m0 + ks * 32 + q * 8 + 4];
        }
        uint4 st[3];
        #pragma unroll
        for (int i = 0; i < 3; ++i) {
            int flat = t + 256 * i;           // 40 rows x 16 chunks = 640
            if (flat < 640) {
                int row = flat >> 4;
                int c8  = (flat & 15) * 8;
                st[i] = *(const uint4*)&Wh2T[(size_t)row * 4096 + m0 + c8];
            }
        }
        bf16x8 aw[4];
        #pragma unroll
        for (int ks = 0; ks < 4; ++ks) {
            float4 g0 = *(const float4*)&F2o[m0 + ks * 32 + q * 8];
            float4 g1 = *(const float4*)&F2o[m0 + ks * 32 + q * 8 + 4];
            float w0 = mexp(a[2 * ks].x,     F1v + g0.x);
            float w1 = mexp(a[2 * ks].y,     F1v + g0.y);
            float w2 = mexp(a[2 * ks].z,     F1v + g0.z);
            float w3 = mexp(a[2 * ks].w,     F1v + g0.w);
            float w4 = mexp(a[2 * ks + 1].x, F1v + g1.x);
            float w5 = mexp(a[2 * ks + 1].y, F1v + g1.y);
            float w6 = mexp(a[2 * ks + 1].z, F1v + g1.z);
            float w7 = mexp(a[2 * ks + 1].w, F1v + g1.w);
            union { u32 u[4]; bf16x8 v; } pk;
            pk.u[0] = pk2(w0, w1); pk.u[1] = pk2(w2, w3);
            pk.u[2] = pk2(w4, w5); pk.u[3] = pk2(w6, w7);
            aw[ks] = pk.v;
        }
        __syncthreads();
        #pragma unroll
        for (int i = 0; i < 3; ++i) {
            int flat = t + 256 * i;
            if (flat < 640) {
                int row = flat >> 4;
                int c8  = (flat & 15) * 8;
                *(uint4*)&whT[row * 136 + c8] = st[i];
            }
        }
        __syncthreads();
        #pragma unroll
        for (int ks = 0; ks < 4; ++ks) {
            int k0 = ks * 32 + q * 8;
            #pragma unroll
            for (int df = 0; df < 3; ++df) {
                bf16x8 b = *(const bf16x8*)&whT[(df * 16 + l15) * 136 + k0];
                acc[df] = __builtin_amdgcn_mfma_f32_16x16x32_bf16(aw[ks], b, acc[df], 0, 0, 0);
            }
            acc[3] = __builtin_amdgcn_mfma_f32_16x16x32_bf16(aw[ks], bones, acc[3], 0, 0, 0);
        }
    }
    #pragma unroll
    for (int r = 0; r < 4; ++r) {
        int n = n0 + wrow + q * 4 + r;
        if (l15 == 0) pz[(size_t)chunk * N + n] = acc[3][r];
        #pragma unroll
        for (int df = 0; df < 3; ++df) {
            int c = df * 16 + l15;
            if (c < NCLASS)
                pacc[((size_t)chunk * N + n) * NCLASS + c] = acc[df][r];
        }
    }
}

// ---------------- K5b: reduce 16 chunks, ELU, log_softmax, f32 store ------------
__global__ __launch_bounds__(256) void k5b_final(const float* __restrict__ pacc,
                                                 const float* __restrict__ pz,
                                                 float* __restrict__ out) {
    const int t = threadIdx.x;
    const int lane = t & 63;
    const int n = blockIdx.x * 4 + (t >> 6);
    float s = 0.f, Z = 0.f;
    #pragma unroll
    for (int ch = 0; ch < 16; ++ch) {
        Z += pz[(size_t)ch * N + n];
        if (lane < NCLASS) s += pacc[(size_t)(ch * N + n) * NCLASS + lane];
    }
    float v;
    if (lane < NCLASS) {
        v = s / fmaxf(Z, 1e-30f);
        v = v > 0.f ? v : __expf(v) - 1.f;
    } else {
        v = -INFINITY;
    }
    float mx = v;
    #pragma unroll
    for (int off = 32; off >= 1; off >>= 1) mx = fmaxf(mx, __shfl_xor(mx, off));
    float ex = (lane < NCLASS) ? __expf(v - mx) : 0.f;
    #pragma unroll
    for (int off = 32; off >= 1; off >>= 1) ex += __shfl_xor(ex, off);
    float lse = mx + __logf(ex);
    if (lane < NCLASS) out[(size_t)n * NCLASS + lane] = v - lse;
}

// ---------------------------------------------------------------------------------
extern "C" void kernel_launch(void* const* d_in, const int* in_sizes, int n_in,
                              void* d_out, int out_size, void* d_ws, size_t ws_size,
                              hipStream_t stream) {
    const float* x   = (const float*)d_in[0];
    const int*   adj = (const int*)d_in[1];
    const float* W1  = (const float*)d_in[2];
    const float* a1  = (const float*)d_in[3];
    const float* Wo  = (const float*)d_in[4];
    const float* ao  = (const float*)d_in[5];

    float* ws    = (float*)d_ws;
    float* h1    = ws;                        // 2,097,152
    float* F1    = h1 + 2097152;              // 32,768
    float* F2    = F1 + 32768;                // 32,768
    float* Wh2   = F2 + 32768;                // 163,840
    float* F1o   = Wh2 + 163840;              // 4,096
    float* F2o   = F1o + 4096;                // 4,096
    float* pz    = F2o + 4096;                // 65,536 (16*4096, k5a)
    float* pz1   = pz + 65536;                // 65,536 (2*8*4096, k3)
    u16*   Wh1T  = (u16*)(pz1 + 65536);       // 2,097,152 u16
    u16*   Wh2T  = Wh1T + 2097152;            // 163,840 u16
    float* R     = (float*)(Wh2T + 163840);   // 4,194,304 f32 shared region
    u16*   xb    = (u16*)R;                   // kcx -> k1m (dies before k3)
    u16*   W1b   = xb + 2097152;              // kcw -> k1m (dies before k3)
    float* pacc1 = R;                         // k3 -> k3b (2*8*4096*64)
    float* pacc  = R;                         // k5a -> k5b (16*4096*40)

    const int* adj0 = adj;                    // layer-2 mask
    const int* adj1 = adj + (size_t)N * N;    // layer-1 mask

    hipLaunchKernelGGL(kcx,       dim3(1024),     dim3(256), 0, stream, x, xb);
    hipLaunchKernelGGL(kcw,       dim3(8, 8),     dim3(256), 0, stream, W1, W1b);
    hipLaunchKernelGGL(k1m_gemm1, dim3(64, 8),    dim3(256), 0, stream, xb, W1b, Wh1T);
    hipLaunchKernelGGL(k2_f12,    dim3(128),      dim3(256), 0, stream, Wh1T, a1, F1, F2);
    hipLaunchKernelGGL(k3_attn1,  dim3(64, 8, 2), dim3(256), 0, stream, adj1, Wh1T, F1, F2, pacc1, pz1);
    hipLaunchKernelGGL(k3b_norm,  dim3(8192),     dim3(256), 0, stream, pacc1, pz1, h1);
    hipLaunchKernelGGL(k4_gemm2,  dim3(1024),     dim3(256), 0, stream, h1, Wo, Wh2);
    hipLaunchKernelGGL(k4b_fo,    dim3(16),       dim3(256), 0, stream, Wh2, ao, F1o, F2o, Wh2T);
    hipLaunchKernelGGL(k5a_attn2, dim3(64, 16),   dim3(256), 0, stream, adj0, Wh2T, F1o, F2o, pacc, pz);
    hipLaunchKernelGGL(k5b_final, dim3(1024),     dim3(256), 0, stream, pacc, pz, (float*)d_out);
}

// Round 10
// 334.782 us; speedup vs baseline: 1.4115x; 1.4115x over previous
//
#include <hip/hip_runtime.h>
#include <hip/hip_bf16.h>

#define N      4096
#define NFEAT  512
#define NHID   64
#define NHEADS 8
#define NCLASS 40
#define ALPHA  0.2f
#define LOG2E  1.44269504f

typedef unsigned short u16;
typedef unsigned int   u32;
typedef __attribute__((ext_vector_type(8))) short bf16x8;
typedef __attribute__((ext_vector_type(4))) float f32x4;

// bf16 bits -> f32
__device__ __forceinline__ float b2f(u16 u) {
    return __uint_as_float(((u32)u) << 16);
}
// RNE-rounded value kept in HIGH 16 bits
__device__ __forceinline__ u32 rnd_hi(float f) {
    u32 u = __float_as_uint(f);
    return u + 0x7FFFu + ((u >> 16) & 1u);
}
// pack two f32 -> two bf16 (lo in low 16) via HW v_cvt_pk_bf16_f32 (gfx950)
__device__ __forceinline__ u32 pk2(float lo, float hi) {
    __hip_bfloat162 h = __float22bfloat162_rn(make_float2(lo, hi));
    return *(u32*)&h;
}
// single f32 -> bf16 bits (RNE)
__device__ __forceinline__ u16 f2b(float f) {
    return (u16)(rnd_hi(f) >> 16);
}
// masked exp2 of leaky-relu in log2 domain: raw v_exp_f32, no OCML guards
__device__ __forceinline__ float mexp(int m, float t) {
    return m ? __builtin_amdgcn_exp2f(fmaxf(t, ALPHA * t)) : 0.f;
}
// constant all-ones bf16 B-fragment (every output column = row sum)
__device__ __forceinline__ bf16x8 ones_frag() {
    union { u16 u[8]; bf16x8 v; } o;
    #pragma unroll
    for (int j = 0; j < 8; ++j) o.u[j] = 0x3F80;
    return o.v;
}

// ---------------- KCX: x f32 -> xb bf16 (same layout) ---------------------------
__global__ __launch_bounds__(256) void kcx(const float* __restrict__ x,
                                           u16* __restrict__ xb) {
    const int g = blockIdx.x * 256 + threadIdx.x;       // 262144 threads x 8 elems
    const size_t base = (size_t)g * 8;
    float4 v0 = *(const float4*)&x[base];
    float4 v1 = *(const float4*)&x[base + 4];
    uint4 o;
    o.x = pk2(v0.x, v0.y); o.y = pk2(v0.z, v0.w);
    o.z = pk2(v1.x, v1.y); o.w = pk2(v1.z, v1.w);
    *(uint4*)&xb[base] = o;
}

// ---------------- KCW: W1 [h][f][d] f32 -> W1b bf16 [h][d][f] -------------------
__global__ __launch_bounds__(256) void kcw(const float* __restrict__ W1,
                                           u16* __restrict__ W1b) {
    __shared__ float ts[64 * 68];   // [f-local][d], pitch 68
    const int t  = threadIdx.x;
    const int f0 = blockIdx.x * 64;
    const int h  = blockIdx.y;
    #pragma unroll
    for (int i = 0; i < 4; ++i) {
        int flat = t + 256 * i;
        int row = flat >> 4;                    // f-local
        int c4  = (flat & 15) * 4;              // d
        *(float4*)&ts[row * 68 + c4] =
            *(const float4*)&W1[((size_t)h * 512 + f0 + row) * 64 + c4];
    }
    __syncthreads();
    const int d  = t >> 2;
    const int fs = (t & 3) * 16;
    u32 p[8];
    #pragma unroll
    for (int j = 0; j < 8; ++j)
        p[j] = pk2(ts[(fs + 2 * j) * 68 + d], ts[(fs + 2 * j + 1) * 68 + d]);
    u32* dst = (u32*)&W1b[((size_t)(h * 64 + d)) * 512 + f0 + fs];
    *(uint4*)dst       = make_uint4(p[0], p[1], p[2], p[3]);
    *(uint4*)(dst + 4) = make_uint4(p[4], p[5], p[6], p[7]);
}

// ---------------- K1M: Wh1T bf16 + fused F1/F2 epilogue -------------------------
// grid (64 n-tiles, 8 heads) x 256; MFMA 16x16x32.
__global__ __launch_bounds__(256, 4) void k1m_gemm1(const u16* __restrict__ xb,
                                                    const u16* __restrict__ W1b,
                                                    const float* __restrict__ a1,
                                                    u16* __restrict__ Wh1T,
                                                    float* __restrict__ F1,
                                                    float* __restrict__ F2) {
    __shared__ u16 xs[64 * 72];    // [n-local][f-chunk], pitch 72
    __shared__ u16 wvs[64 * 72];   // [d][f-chunk]
    const int t    = threadIdx.x;
    const int n0   = blockIdx.x * 64;
    const int h    = blockIdx.y;
    const int lane = t & 63;
    const int l15  = lane & 15;
    const int q    = lane >> 4;
    const int wrow = (t >> 6) * 16;
    f32x4 acc[4];
    #pragma unroll
    for (int df = 0; df < 4; ++df)
        #pragma unroll
        for (int r = 0; r < 4; ++r) acc[df][r] = 0.f;
    for (int f0 = 0; f0 < 512; f0 += 64) {
        uint4 sx[2], sw[2];
        #pragma unroll
        for (int i = 0; i < 2; ++i) {
            int flat = t + 256 * i;
            int row = flat >> 3;
            int c8  = (flat & 7) * 8;
            sx[i] = *(const uint4*)&xb[(size_t)(n0 + row) * 512 + f0 + c8];
            sw[i] = *(const uint4*)&W1b[((size_t)(h * 64 + row)) * 512 + f0 + c8];
        }
        __syncthreads();
        #pragma unroll
        for (int i = 0; i < 2; ++i) {
            int flat = t + 256 * i;
            int row = flat >> 3;
            int c8  = (flat & 7) * 8;
            *(uint4*)&xs[row * 72 + c8]  = sx[i];
            *(uint4*)&wvs[row * 72 + c8] = sw[i];
        }
        __syncthreads();
        #pragma unroll
        for (int ks = 0; ks < 2; ++ks) {
            int k0 = ks * 32 + q * 8;
            bf16x8 a = *(const bf16x8*)&xs[(wrow + l15) * 72 + k0];
            #pragma unroll
            for (int df = 0; df < 4; ++df) {
                bf16x8 b = *(const bf16x8*)&wvs[(df * 16 + l15) * 72 + k0];
                acc[df] = __builtin_amdgcn_mfma_f32_16x16x32_bf16(a, b, acc[df], 0, 0, 0);
            }
        }
    }
    // Wh1T store: C row = q*4+r (n-local), col = l15 (d-local)
    #pragma unroll
    for (int df = 0; df < 4; ++df) {
        uint2 o;
        o.x = pk2(acc[df][0], acc[df][1]);
        o.y = pk2(acc[df][2], acc[df][3]);
        *(uint2*)&Wh1T[((size_t)(h * 64 + df * 16 + l15)) * 4096 + n0 + wrow + q * 4] = o;
    }
    // fused F1/F2: f = sum_d Wh[n][h*64+d] * a1[h,{0,1},d], reduce over l15 group
    float a1v[4], a2v[4];
    #pragma unroll
    for (int df = 0; df < 4; ++df) {
        a1v[df] = a1[h * 128 + df * 16 + l15];
        a2v[df] = a1[h * 128 + 64 + df * 16 + l15];
    }
    #pragma unroll
    for (int r = 0; r < 4; ++r) {
        float s1 = 0.f, s2 = 0.f;
        #pragma unroll
        for (int df = 0; df < 4; ++df) {
            s1 += acc[df][r] * a1v[df];
            s2 += acc[df][r] * a2v[df];
        }
        #pragma unroll
        for (int off = 8; off >= 1; off >>= 1) {
            s1 += __shfl_xor(s1, off);
            s2 += __shfl_xor(s2, off);
        }
        if (l15 == 0) {
            int n = n0 + wrow + q * 4 + r;
            F1[h * 4096 + n] = s1 * LOG2E;
            F2[h * 4096 + n] = s2 * LOG2E;
        }
    }
}

// ---------------- K3: layer-1 attention partials via MFMA -----------------------
// R8-proven structure (LDS wbf, adj reg prefetch) + ones-frag denominator.
// LDS 35 KB -> 4 blocks/CU. grid (64 n-tiles, 8 heads, 2 m-chunks) x 256.
__global__ __launch_bounds__(256, 4) void k3_attn1(const int* __restrict__ adj1,
                                                   const u16* __restrict__ Wh1T,
                                                   const float* __restrict__ F1,
                                                   const float* __restrict__ F2,
                                                   float* __restrict__ pacc1,
                                                   float* __restrict__ pz1) {
    __shared__ u16  wbf[64 * 136];    // A-tile, pitch 136
    __shared__ u16  whT[64 * 136];    // B-tile, data rows d=0..63 only
    __shared__ float f1s[64];
    const int t     = threadIdx.x;
    const int n0    = blockIdx.x * 64;
    const int h     = blockIdx.y;
    const int chunk = blockIdx.z;
    const int lane  = t & 63;
    const int l15   = lane & 15;
    const int q     = lane >> 4;
    const int wrow  = (t >> 6) * 16;
    const int c4    = (t & 31) * 4;           // mask-gen: 4 consecutive cols
    const int rg    = t >> 5;                 // mask-gen: row group 0..7
    const bf16x8 bones = ones_frag();
    if (t < 64) f1s[t] = F1[h * N + n0 + t];
    f32x4 acc[5];
    #pragma unroll
    for (int df = 0; df < 5; ++df)
        #pragma unroll
        for (int r = 0; r < 4; ++r) acc[df][r] = 0.f;

    const int mbeg = chunk * 2048;
    // preload iter-0 adj tile into registers (8 x int4 = 32 VGPRs)
    int4 aprev[8];
    #pragma unroll
    for (int i = 0; i < 8; ++i)
        aprev[i] = *(const int4*)&adj1[(size_t)(n0 + rg + 8 * i) * N + mbeg + c4];
    __syncthreads();

    for (int m0 = mbeg; m0 < mbeg + 2048; m0 += 128) {
        // ---- mask-gen from prefetched adj regs -> wbf (HW exp2 + HW bf16 pack) ----
        float4 F2v = *(const float4*)&F2[h * N + m0 + c4];
        #pragma unroll
        for (int i = 0; i < 8; ++i) {
            int rr = rg + 8 * i;
            int4 a4 = aprev[i];
            float f1v = f1s[rr];
            float w0 = mexp(a4.x, f1v + F2v.x);
            float w1 = mexp(a4.y, f1v + F2v.y);
            float w2 = mexp(a4.z, f1v + F2v.z);
            float w3 = mexp(a4.w, f1v + F2v.w);
            uint2 pk;
            pk.x = pk2(w0, w1);
            pk.y = pk2(w2, w3);
            *(uint2*)&wbf[rr * 136 + c4] = pk;
        }
        // ---- prefetch next iter's adj (wraps on last iter; harmless) ----
        int mn = (m0 + 128 < mbeg + 2048) ? m0 + 128 : mbeg;
        #pragma unroll
        for (int i = 0; i < 8; ++i)
            aprev[i] = *(const int4*)&adj1[(size_t)(n0 + rg + 8 * i) * N + mn + c4];
        // ---- stage B-tile ----
        #pragma unroll
        for (int i = 0; i < 4; ++i) {
            int flat = t + 256 * i;           // 64 rows x 16 chunks
            int row = flat >> 4;
            int c8  = (flat & 15) * 8;
            *(uint4*)&whT[row * 136 + c8] =
                *(const uint4*)&Wh1T[((size_t)(h * 64 + row)) * 4096 + m0 + c8];
        }
        __syncthreads();
        // ---- compute: 4 K-steps x (4 data frags + ones frag) ----
        #pragma unroll
        for (int ks = 0; ks < 4; ++ks) {
            int k0 = ks * 32 + q * 8;
            bf16x8 a = *(const bf16x8*)&wbf[(wrow + l15) * 136 + k0];
            #pragma unroll
            for (int df = 0; df < 4; ++df) {
                bf16x8 b = *(const bf16x8*)&whT[(df * 16 + l15) * 136 + k0];
                acc[df] = __builtin_amdgcn_mfma_f32_16x16x32_bf16(a, b, acc[df], 0, 0, 0);
            }
            acc[4] = __builtin_amdgcn_mfma_f32_16x16x32_bf16(a, bones, acc[4], 0, 0, 0);
        }
        __syncthreads();
    }
    // raw partials; denominator = acc[4] (all columns equal the row sum)
    const size_t rowbase = (size_t)(chunk * 8 + h) * 4096 + n0;
    #pragma unroll
    for (int r = 0; r < 4; ++r) {
        int nl = wrow + q * 4 + r;
        if (l15 == 0) pz1[rowbase + nl] = acc[4][r];
        #pragma unroll
        for (int df = 0; df < 4; ++df)
            pacc1[(rowbase + nl) * 64 + df * 16 + l15] = acc[df][r];
    }
}

// ---------------- K3b: reduce 2 chunks, normalize, ELU -> h1 f32 ----------------
__global__ __launch_bounds__(256) void k3b_norm(const float* __restrict__ pacc1,
                                                const float* __restrict__ pz1,
                                                float* __restrict__ h1) {
    const int g = blockIdx.x * 256 + threadIdx.x;
    const int d = g & 63;
    const int h = (g >> 6) & 7;
    const int n = g >> 9;
    const size_t i0 = (size_t)h * 4096 + n;
    float s = pacc1[i0 * 64 + d] + pacc1[(i0 + 8 * 4096) * 64 + d];
    float z = pz1[i0] + pz1[i0 + 8 * 4096];
    float v = s / fmaxf(z, 1e-30f);
    h1[(size_t)n * 512 + h * 64 + d] = v > 0.f ? v : __expf(v) - 1.f;
}

// ---------------- K4: fused Wh2 GEMM + F1o/F2o + Wh2T bf16 ----------------------
// wave = one n (lane = c); grid 1024 x 256.
__global__ __launch_bounds__(256) void k4_gemm2(const float* __restrict__ h1,
                                                const float* __restrict__ Wo,
                                                const float* __restrict__ ao,
                                                float* __restrict__ F1o,
                                                float* __restrict__ F2o,
                                                u16* __restrict__ Wh2T) {
    const int t = threadIdx.x;
    const int c = t & 63;
    const int n = blockIdx.x * 4 + (t >> 6);
    float acc = 0.f;
    if (c < NCLASS) {
        const float* hrow = &h1[(size_t)n * 512];
        #pragma unroll 8
        for (int f = 0; f < 512; ++f)
            acc += hrow[f] * Wo[f * NCLASS + c];
        Wh2T[(size_t)c * 4096 + n] = f2b(acc);
    }
    float s1 = (c < NCLASS) ? acc * ao[c] : 0.f;
    float s2 = (c < NCLASS) ? acc * ao[NCLASS + c] : 0.f;
    #pragma unroll
    for (int off = 32; off >= 1; off >>= 1) {
        s1 += __shfl_xor(s1, off);
        s2 += __shfl_xor(s2, off);
    }
    if (c == 0) {
        F1o[n] = s1 * LOG2E;
        F2o[n] = s2 * LOG2E;
    }
}

// ---------------- K5a: layer-2 attention partials via MFMA ----------------------
// R8 structure + ones-frag. LDS 30.7 KB -> 5 blocks/CU at (256,5).
// grid (64 n-tiles, 16 m-chunks) x 256.
__global__ __launch_bounds__(256, 5) void k5a_attn2(const int* __restrict__ adj0,
                                                    const u16* __restrict__ Wh2T,
                                                    const float* __restrict__ F1o,
                                                    const float* __restrict__ F2o,
                                                    float* __restrict__ pacc,
                                                    float* __restrict__ pz) {
    __shared__ u16  wbf[64 * 136];
    __shared__ u16  whT[48 * 136];    // rows 0..39 data, 40..47 zero
    __shared__ float f1s[64];
    const int t     = threadIdx.x;
    const int n0    = blockIdx.x * 64;
    const int chunk = blockIdx.y;
    const int mbase = chunk * 256;
    const int lane  = t & 63;
    const int l15   = lane & 15;
    const int q     = lane >> 4;
    const int wrow  = (t >> 6) * 16;
    const int c4    = (t & 31) * 4;
    const int rg    = t >> 5;
    const bf16x8 bones = ones_frag();
    if (t < 64) f1s[t] = F1o[n0 + t];
    // zero pad rows 40..47 (read by df=2 frag, lanes l15>=8)
    #pragma unroll
    for (int i = 0; i < 5; ++i) {
        int idx = t + 256 * i;                // 8*136 = 1088
        if (idx < 1088) whT[40 * 136 + idx] = 0;
    }
    f32x4 acc[4];
    #pragma unroll
    for (int df = 0; df < 4; ++df)
        #pragma unroll
        for (int r = 0; r < 4; ++r) acc[df][r] = 0.f;
    int4 aprev[8];
    #pragma unroll
    for (int i = 0; i < 8; ++i)
        aprev[i] = *(const int4*)&adj0[(size_t)(n0 + rg + 8 * i) * N + mbase + c4];
    __syncthreads();

    for (int mt = 0; mt < 2; ++mt) {
        int m0 = mbase + mt * 128;
        float4 F2v = *(const float4*)&F2o[m0 + c4];
        #pragma unroll
        for (int i = 0; i < 8; ++i) {
            int rr = rg + 8 * i;
            int4 a4 = aprev[i];
            float f1v = f1s[rr];
            float w0 = mexp(a4.x, f1v + F2v.x);
            float w1 = mexp(a4.y, f1v + F2v.y);
            float w2 = mexp(a4.z, f1v + F2v.z);
            float w3 = mexp(a4.w, f1v + F2v.w);
            uint2 pk;
            pk.x = pk2(w0, w1);
            pk.y = pk2(w2, w3);
            *(uint2*)&wbf[rr * 136 + c4] = pk;
        }
        int mn = mbase + ((mt + 1) & 1) * 128;
        #pragma unroll
        for (int i = 0; i < 8; ++i)
            aprev[i] = *(const int4*)&adj0[(size_t)(n0 + rg + 8 * i) * N + mn + c4];
        #pragma unroll
        for (int i = 0; i < 3; ++i) {
            int flat = t + 256 * i;           // 40 rows x 16 chunks = 640
            if (flat < 640) {
                int row = flat >> 4;
                int c8  = (flat & 15) * 8;
                *(uint4*)&whT[row * 136 + c8] =
                    *(const uint4*)&Wh2T[(size_t)row * 4096 + m0 + c8];
            }
        }
        __syncthreads();
        #pragma unroll
        for (int ks = 0; ks < 4; ++ks) {
            int k0 = ks * 32 + q * 8;
            bf16x8 a = *(const bf16x8*)&wbf[(wrow + l15) * 136 + k0];
            #pragma unroll
            for (int df = 0; df < 3; ++df) {
                bf16x8 b = *(const bf16x8*)&whT[(df * 16 + l15) * 136 + k0];
                acc[df] = __builtin_amdgcn_mfma_f32_16x16x32_bf16(a, b, acc[df], 0, 0, 0);
            }
            acc[3] = __builtin_amdgcn_mfma_f32_16x16x32_bf16(a, bones, acc[3], 0, 0, 0);
        }
        __syncthreads();
    }
    #pragma unroll
    for (int r = 0; r < 4; ++r) {
        int n = n0 + wrow + q * 4 + r;
        if (l15 == 0) pz[(size_t)chunk * N + n] = acc[3][r];
        #pragma unroll
        for (int df = 0; df < 3; ++df) {
            int c = df * 16 + l15;
            if (c < NCLASS)
                pacc[((size_t)chunk * N + n) * NCLASS + c] = acc[df][r];
        }
    }
}

// ---------------- K5b: reduce 16 chunks, ELU, log_softmax, f32 store ------------
__global__ __launch_bounds__(256) void k5b_final(const float* __restrict__ pacc,
                                                 const float* __restrict__ pz,
                                                 float* __restrict__ out) {
    const int t = threadIdx.x;
    const int lane = t & 63;
    const int n = blockIdx.x * 4 + (t >> 6);
    float s = 0.f, Z = 0.f;
    #pragma unroll
    for (int ch = 0; ch < 16; ++ch) {
        Z += pz[(size_t)ch * N + n];
        if (lane < NCLASS) s += pacc[(size_t)(ch * N + n) * NCLASS + lane];
    }
    float v;
    if (lane < NCLASS) {
        v = s / fmaxf(Z, 1e-30f);
        v = v > 0.f ? v : __expf(v) - 1.f;
    } else {
        v = -INFINITY;
    }
    float mx = v;
    #pragma unroll
    for (int off = 32; off >= 1; off >>= 1) mx = fmaxf(mx, __shfl_xor(mx, off));
    float ex = (lane < NCLASS) ? __expf(v - mx) : 0.f;
    #pragma unroll
    for (int off = 32; off >= 1; off >>= 1) ex += __shfl_xor(ex, off);
    float lse = mx + __logf(ex);
    if (lane < NCLASS) out[(size_t)n * NCLASS + lane] = v - lse;
}

// ---------------------------------------------------------------------------------
extern "C" void kernel_launch(void* const* d_in, const int* in_sizes, int n_in,
                              void* d_out, int out_size, void* d_ws, size_t ws_size,
                              hipStream_t stream) {
    const float* x   = (const float*)d_in[0];
    const int*   adj = (const int*)d_in[1];
    const float* W1  = (const float*)d_in[2];
    const float* a1  = (const float*)d_in[3];
    const float* Wo  = (const float*)d_in[4];
    const float* ao  = (const float*)d_in[5];

    float* ws    = (float*)d_ws;
    float* h1    = ws;                        // 2,097,152
    float* F1    = h1 + 2097152;              // 32,768
    float* F2    = F1 + 32768;                // 32,768
    float* F1o   = F2 + 32768;                // 4,096
    float* F2o   = F1o + 4096;                // 4,096
    float* pz    = F2o + 4096;                // 65,536 (16*4096, k5a)
    float* pz1   = pz + 65536;                // 65,536 (2*8*4096, k3)
    u16*   Wh1T  = (u16*)(pz1 + 65536);       // 2,097,152 u16
    u16*   Wh2T  = Wh1T + 2097152;            // 163,840 u16
    float* R     = (float*)(Wh2T + 163840);   // 4,194,304 f32 shared region
    u16*   xb    = (u16*)R;                   // kcx -> k1m (dies before k3)
    u16*   W1b   = xb + 2097152;              // kcw -> k1m (dies before k3)
    float* pacc1 = R;                         // k3 -> k3b (2*8*4096*64)
    float* pacc  = R;                         // k5a -> k5b (16*4096*40)

    const int* adj0 = adj;                    // layer-2 mask
    const int* adj1 = adj + (size_t)N * N;    // layer-1 mask

    hipLaunchKernelGGL(kcx,       dim3(1024),     dim3(256), 0, stream, x, xb);
    hipLaunchKernelGGL(kcw,       dim3(8, 8),     dim3(256), 0, stream, W1, W1b);
    hipLaunchKernelGGL(k1m_gemm1, dim3(64, 8),    dim3(256), 0, stream, xb, W1b, a1, Wh1T, F1, F2);
    hipLaunchKernelGGL(k3_attn1,  dim3(64, 8, 2), dim3(256), 0, stream, adj1, Wh1T, F1, F2, pacc1, pz1);
    hipLaunchKernelGGL(k3b_norm,  dim3(8192),     dim3(256), 0, stream, pacc1, pz1, h1);
    hipLaunchKernelGGL(k4_gemm2,  dim3(1024),     dim3(256), 0, stream, h1, Wo, ao, F1o, F2o, Wh2T);
    hipLaunchKernelGGL(k5a_attn2, dim3(64, 16),   dim3(256), 0, stream, adj0, Wh2T, F1o, F2o, pacc, pz);
    hipLaunchKernelGGL(k5b_final, dim3(1024),     dim3(256), 0, stream, pacc, pz, (float*)d_out);
}